// Round 4
// baseline (501.367 us; speedup 1.0000x reference)
//
#include <hip/hip_runtime.h>
#include <cmath>

// Problem constants
#define TT 8192
#define NE 256
#define ND 7168
#define NGRP 8
#define TOPKG 4
#define TOPK 8
#define ROUTE_SCALE 2.5f

#define NKT (ND / 32)      // 224 k-tiles of 32
#define NNT (NE / 16)      // 16 n-tiles of 16
#define TM 64              // tokens per block (shared by all 4 waves)
#define BSTRN ((size_t)NKT * 512)   // halves between 16-expert n-tiles in frag buffer

typedef _Float16 half8_ __attribute__((ext_vector_type(8)));
typedef float float4_ __attribute__((ext_vector_type(4)));

// ---------------------------------------------------------------------------
// w (fp32 [E][D]) -> fragment-ordered fp16 hi/lo.
// B-frag for mfma_f32_16x16x32_f16: lane holds B[k=quad*8+j][n=lane&15].
__global__ __launch_bounds__(256) void conv_w_kernel(
    const float* __restrict__ w, _Float16* __restrict__ whF,
    _Float16* __restrict__ wlF)
{
    const int gid  = blockIdx.x * 256 + threadIdx.x;   // NNT*NKT*64 total
    const int lane = gid & 63;
    const int pair = gid >> 6;            // nt*NKT + kt
    const int kt   = pair % NKT;
    const int nt   = pair / NKT;
    const int n  = nt * 16 + (lane & 15);
    const int kb = kt * 32 + (lane >> 4) * 8;
    const float* src = w + (size_t)n * ND + kb;
    const float4 v0 = *reinterpret_cast<const float4*>(src);
    const float4 v1 = *reinterpret_cast<const float4*>(src + 4);
    const float vs[8] = {v0.x, v0.y, v0.z, v0.w, v1.x, v1.y, v1.z, v1.w};
    half8_ h, l;
    #pragma unroll
    for (int j = 0; j < 8; ++j) {
        const _Float16 hi = (_Float16)vs[j];
        h[j] = hi;
        l[j] = (_Float16)(vs[j] - (float)hi);
    }
    const size_t off = ((size_t)pair * 64 + lane) * 8;
    *reinterpret_cast<half8_*>(whF + off) = h;
    *reinterpret_cast<half8_*>(wlF + off) = l;
}

// ---------------------------------------------------------------------------
// Barrier-free split-fp16 MFMA GEMM.
// No LDS: each wave fragment-gathers its A (x) directly from global (the 4
// waves of a block share the same 64 tokens -> L1 dedupes), converts
// fp32 -> hi/lo fp16 in registers. No __syncthreads in the K-loop, so
// register prefetches (x: 2 chunks ahead, B: 1 chunk ahead) stay in flight
// under compiler-placed fine-grained vmcnt.
__global__ __launch_bounds__(256, 2) void gemm_kernel(
    const float* __restrict__ x, const _Float16* __restrict__ whF,
    const _Float16* __restrict__ wlF, float* __restrict__ partial,
    int K_slice)
{
    const int tid  = threadIdx.x;
    const int lane = tid & 63;
    const int nq   = tid >> 6;            // wave id -> 64-expert quarter
    const int t0   = blockIdx.x * TM;
    const int ks   = blockIdx.y;
    const int kbeg = ks * K_slice;
    const int kt0  = kbeg >> 5;
    const int nchunks = K_slice >> 5;     // even for all kslices (28/56/112/224)

    const int q  = lane >> 4;             // quad -> k offset q*8
    const int cn = lane & 15;             // token row within 16-tile

    float4_ acc[4][4];
    #pragma unroll
    for (int i = 0; i < 4; ++i)
        #pragma unroll
        for (int j = 0; j < 4; ++j) acc[i][j] = (float4_)0.0f;

    // Lane's A-gather base: row (t0+cn), k offset q*8 within chunk.
    const float* xl = x + (size_t)(t0 + cn) * ND + kbeg + q * 8;
    const _Float16* bh0 = whF + (size_t)(nq * 4) * BSTRN + (size_t)kt0 * 512 + lane * 8;
    const _Float16* bl0 = wlF + (size_t)(nq * 4) * BSTRN + (size_t)kt0 * 512 + lane * 8;

    float4 xv[2][4][2];    // [slot][m-tile][half]: raw fp32 x fragments
    half8_ Bf[2][8];       // [slot][ntl*2 + (0=hi,1=lo)]

    // Prologue: x(0)->slot0, x(1)->slot1, B(0)->slot0.
    #pragma unroll
    for (int mt = 0; mt < 4; ++mt) {
        const float* p = xl + (size_t)(mt * 16) * ND;
        xv[0][mt][0] = *reinterpret_cast<const float4*>(p);
        xv[0][mt][1] = *reinterpret_cast<const float4*>(p + 4);
        xv[1][mt][0] = *reinterpret_cast<const float4*>(p + 32);
        xv[1][mt][1] = *reinterpret_cast<const float4*>(p + 36);
    }
    #pragma unroll
    for (int ntl = 0; ntl < 4; ++ntl) {
        Bf[0][ntl * 2 + 0] = *reinterpret_cast<const half8_*>(bh0 + (size_t)ntl * BSTRN);
        Bf[0][ntl * 2 + 1] = *reinterpret_cast<const half8_*>(bl0 + (size_t)ntl * BSTRN);
    }

#define STEP(P, C)                                                             \
    {                                                                          \
        /* 1. convert x(C) (loaded 2 iters ago) -> A frags */                  \
        half8_ ah[4], al[4];                                                   \
        _Pragma("unroll")                                                      \
        for (int mt = 0; mt < 4; ++mt) {                                       \
            const float4 v0 = xv[P][mt][0];                                    \
            const float4 v1 = xv[P][mt][1];                                    \
            const float vs[8] = {v0.x, v0.y, v0.z, v0.w,                       \
                                 v1.x, v1.y, v1.z, v1.w};                      \
            _Pragma("unroll")                                                  \
            for (int j = 0; j < 8; ++j) {                                      \
                const _Float16 hi = (_Float16)vs[j];                           \
                ah[mt][j] = hi;                                                \
                al[mt][j] = (_Float16)(vs[j] - (float)hi);                     \
            }                                                                  \
        }                                                                      \
        /* 2. issue x(C+2) -> slot P (regs just freed by conversion) */        \
        if ((C) + 2 < nchunks) {                                               \
            _Pragma("unroll")                                                  \
            for (int mt = 0; mt < 4; ++mt) {                                   \
                const float* p = xl + (size_t)(mt * 16) * ND + ((C) + 2) * 32; \
                xv[P][mt][0] = *reinterpret_cast<const float4*>(p);            \
                xv[P][mt][1] = *reinterpret_cast<const float4*>(p + 4);        \
            }                                                                  \
        }                                                                      \
        /* 3. issue B(C+1) -> slot P^1 */                                      \
        if ((C) + 1 < nchunks) {                                               \
            _Pragma("unroll")                                                  \
            for (int ntl = 0; ntl < 4; ++ntl) {                                \
                Bf[(P) ^ 1][ntl * 2 + 0] = *reinterpret_cast<const half8_*>(   \
                    bh0 + (size_t)ntl * BSTRN + ((C) + 1) * 512);              \
                Bf[(P) ^ 1][ntl * 2 + 1] = *reinterpret_cast<const half8_*>(   \
                    bl0 + (size_t)ntl * BSTRN + ((C) + 1) * 512);              \
            }                                                                  \
        }                                                                      \
        /* 4. MFMA, product-major: 16 independent between dependent accs */    \
        _Pragma("unroll")                                                      \
        for (int mt = 0; mt < 4; ++mt)                                         \
            _Pragma("unroll")                                                  \
            for (int ntl = 0; ntl < 4; ++ntl)                                  \
                acc[mt][ntl] = __builtin_amdgcn_mfma_f32_16x16x32_f16(         \
                    ah[mt], Bf[P][ntl * 2 + 0], acc[mt][ntl], 0, 0, 0);        \
        _Pragma("unroll")                                                      \
        for (int mt = 0; mt < 4; ++mt)                                         \
            _Pragma("unroll")                                                  \
            for (int ntl = 0; ntl < 4; ++ntl)                                  \
                acc[mt][ntl] = __builtin_amdgcn_mfma_f32_16x16x32_f16(         \
                    al[mt], Bf[P][ntl * 2 + 0], acc[mt][ntl], 0, 0, 0);        \
        _Pragma("unroll")                                                      \
        for (int mt = 0; mt < 4; ++mt)                                         \
            _Pragma("unroll")                                                  \
            for (int ntl = 0; ntl < 4; ++ntl)                                  \
                acc[mt][ntl] = __builtin_amdgcn_mfma_f32_16x16x32_f16(         \
                    ah[mt], Bf[P][ntl * 2 + 1], acc[mt][ntl], 0, 0, 0);        \
    }

    for (int c = 0; c < nchunks; c += 2) {
        STEP(0, c)
        STEP(1, c + 1)
    }
#undef STEP

    // Epilogue: C/D layout col=lane&15, row=quad*4+reg
    #pragma unroll
    for (int mt = 0; mt < 4; ++mt)
        #pragma unroll
        for (int r = 0; r < 4; ++r) {
            const int t = t0 + mt * 16 + q * 4 + r;
            float* rowp = partial + ((size_t)ks * TT + t) * NE;
            #pragma unroll
            for (int ntl = 0; ntl < 4; ++ntl)
                rowp[nq * 64 + ntl * 16 + cn] = acc[mt][ntl][r];
        }
}

// ---------------------------------------------------------------------------
// Routing: one 64-lane wave per token; lane handles 4 experts.
__global__ __launch_bounds__(256) void routing_kernel(
    const float* __restrict__ partial, const float* __restrict__ bias,
    float* __restrict__ out_w, float* __restrict__ out_i, int kslices)
{
    const int lane = threadIdx.x & 63;
    const int t = blockIdx.x * 4 + (threadIdx.x >> 6);

    float4 a = make_float4(0.f, 0.f, 0.f, 0.f);
    for (int s = 0; s < kslices; ++s) {
        const float4 p = *reinterpret_cast<const float4*>(
            partial + ((size_t)s * TT + t) * NE + lane * 4);
        a.x += p.x; a.y += p.y; a.z += p.z; a.w += p.w;
    }
    const float4 b4 = *reinterpret_cast<const float4*>(bias + lane * 4);
    const float lg[4] = {a.x, a.y, a.z, a.w};
    const float bs[4] = {b4.x, b4.y, b4.z, b4.w};
    float sg[4], sv[4];
    #pragma unroll
    for (int j = 0; j < 4; ++j) {
        sg[j] = 1.0f / (1.0f + expf(-lg[j]));   // original sigmoid score
        sv[j] = sg[j] + bs[j];                  // biased score
    }

    // Per-group (8 lanes = 32 experts) top-2 sum
    float m1 = -1e30f, m2 = -1e30f;
    #pragma unroll
    for (int j = 0; j < 4; ++j) {
        if (sv[j] > m1)      { m2 = m1; m1 = sv[j]; }
        else if (sv[j] > m2) { m2 = sv[j]; }
    }
    #pragma unroll
    for (int off = 1; off <= 4; off <<= 1) {
        const float o1 = __shfl_xor(m1, off, 64);
        const float o2 = __shfl_xor(m2, off, 64);
        if (o1 > m1) { m2 = fmaxf(m1, o2); m1 = o1; }
        else         { m2 = fmaxf(m2, o1); }
    }
    const float gs = m1 + m2;

    // All 8 group scores on every lane; serial top-4 (lowest index on ties)
    float gv[NGRP];
    #pragma unroll
    for (int g = 0; g < NGRP; ++g) gv[g] = __shfl(gs, g * 8, 64);
    unsigned keep = 0;
    #pragma unroll
    for (int r = 0; r < TOPKG; ++r) {
        int best = 0; float bvv = -1e30f;
        #pragma unroll
        for (int g = 0; g < NGRP; ++g) {
            const bool taken = (keep >> g) & 1u;
            if (!taken && gv[g] > bvv) { bvv = gv[g]; best = g; }
        }
        keep |= 1u << best;
    }

    // Masked scores (exact 0.0f for dropped groups, matching sg*mask)
    const bool kept = (keep >> (lane >> 3)) & 1u;
    float rv[4];
    #pragma unroll
    for (int j = 0; j < 4; ++j) rv[j] = kept ? sv[j] : 0.0f;

    // 8x wave argmax extraction carrying (biased val, idx, orig sigmoid)
    float wsum = 0.f, myw = 0.f;
    int myi = 0;
    #pragma unroll
    for (int r = 0; r < TOPK; ++r) {
        float bv = -1e30f, bo = 0.f; int bi = 0x7fffffff;
        #pragma unroll
        for (int j = 0; j < 4; ++j)
            if (rv[j] > bv) { bv = rv[j]; bi = lane * 4 + j; bo = sg[j]; }
        #pragma unroll
        for (int off = 1; off < 64; off <<= 1) {
            const float ov = __shfl_xor(bv, off, 64);
            const int   oi = __shfl_xor(bi, off, 64);
            const float oo = __shfl_xor(bo, off, 64);
            if (ov > bv || (ov == bv && oi < bi)) { bv = ov; bi = oi; bo = oo; }
        }
        if ((bi >> 2) == lane) rv[bi & 3] = -1e30f;   // remove winner
        wsum += bo;
        if (lane == r) { myw = bo; myi = bi; }
    }
    const float scale = ROUTE_SCALE / wsum;
    if (lane < TOPK) {
        out_w[(size_t)t * TOPK + lane] = myw * scale;
        out_i[(size_t)t * TOPK + lane] = (float)myi;  // fp32-encoded indices
    }
}

// ---------------------------------------------------------------------------
extern "C" void kernel_launch(void* const* d_in, const int* in_sizes, int n_in,
                              void* d_out, int out_size, void* d_ws, size_t ws_size,
                              hipStream_t stream) {
    const float* x    = (const float*)d_in[0];
    const float* w    = (const float*)d_in[1];
    const float* bias = (const float*)d_in[2];

    float* out_w = (float*)d_out;
    float* out_i = (float*)d_out + (size_t)TT * TOPK;

    // ws layout: whF | wlF | partial[kslices][TT][NE]
    const size_t wfrag_bytes = (size_t)NE * ND * sizeof(_Float16);  // 3.67 MB
    _Float16* whF = (_Float16*)d_ws;
    _Float16* wlF = (_Float16*)((char*)d_ws + wfrag_bytes);
    float* partial = (float*)((char*)d_ws + 2 * wfrag_bytes);

    const size_t part1 = (size_t)TT * NE * sizeof(float);           // 8 MB
    int kslices = 1;
    if      (ws_size >= 2 * wfrag_bytes + 8 * part1) kslices = 8;
    else if (ws_size >= 2 * wfrag_bytes + 4 * part1) kslices = 4;
    else if (ws_size >= 2 * wfrag_bytes + 2 * part1) kslices = 2;
    const int K_slice = ND / kslices;

    conv_w_kernel<<<(NNT * NKT * 64) / 256, 256, 0, stream>>>(w, whF, wlF);

    dim3 ggrid(TT / TM, kslices);
    gemm_kernel<<<ggrid, 256, 0, stream>>>(x, whF, wlF, partial, K_slice);

    routing_kernel<<<TT / 4, 256, 0, stream>>>(partial, bias, out_w, out_i, kslices);
}

// Round 5
// 403.700 us; speedup vs baseline: 1.2419x; 1.2419x over previous
//
#include <hip/hip_runtime.h>
#include <cmath>

// Problem constants
#define TT 8192
#define NE 256
#define ND 7168
#define NGRP 8
#define TOPKG 4
#define TOPK 8
#define ROUTE_SCALE 2.5f

#define NKT16 (ND / 16)    // 448 k-tiles of 16 (MFMA K)
#define NNT32 (NE / 32)    // 8 n-tiles of 32 (one per wave)
#define TM 64              // tokens per block
#define XP 40              // halves per LDS row (32 + 8 pad)

typedef _Float16 half8_ __attribute__((ext_vector_type(8)));
typedef _Float16 half4_ __attribute__((ext_vector_type(4)));
typedef float float16_ __attribute__((ext_vector_type(16)));

// ---------------------------------------------------------------------------
// w (fp32 [E][D]) -> fragment-ordered fp16 hi/lo for mfma_f32_32x32x16_f16.
// B-frag: lane holds B[k = kt16*16 + (lane>>5)*8 + j][n = nt*32 + (lane&31)].
// Buffer offset: ((nt*NKT16 + kt16)*64 + lane)*8.
__global__ __launch_bounds__(256) void conv_w_kernel(
    const float* __restrict__ w, _Float16* __restrict__ whF,
    _Float16* __restrict__ wlF)
{
    const int gid  = blockIdx.x * 256 + threadIdx.x;   // NNT32*NKT16*64 total
    const int lane = gid & 63;
    const int pair = gid >> 6;            // nt*NKT16 + kt16
    const int kt16 = pair % NKT16;
    const int nt   = pair / NKT16;
    const int n  = nt * 32 + (lane & 31);
    const int kb = kt16 * 16 + (lane >> 5) * 8;
    const float* src = w + (size_t)n * ND + kb;
    const float4 v0 = *reinterpret_cast<const float4*>(src);
    const float4 v1 = *reinterpret_cast<const float4*>(src + 4);
    const float vs[8] = {v0.x, v0.y, v0.z, v0.w, v1.x, v1.y, v1.z, v1.w};
    half8_ h, l;
    #pragma unroll
    for (int j = 0; j < 8; ++j) {
        const _Float16 hi = (_Float16)vs[j];
        h[j] = hi;
        l[j] = (_Float16)(vs[j] - (float)hi);
    }
    const size_t off = ((size_t)pair * 64 + lane) * 8;
    *reinterpret_cast<half8_*>(whF + off) = h;
    *reinterpret_cast<half8_*>(wlF + off) = l;
}

// ---------------------------------------------------------------------------
// Split-fp16 MFMA GEMM, 512-thread blocks (8 waves), wave = 64 tok x 32 exp,
// mfma_f32_32x32x16_f16 (2 m-tiles of 32). Round-3 pipeline: LDS dbuf for x,
// ONE barrier per 32-k chunk, x prefetched 2 chunks ahead (coalesced), B
// prefetched 1 chunk ahead from fragment-ordered L2-resident buffers.
// Register budget ~120/wave -> 4 waves/SIMD (16 waves/CU).
__global__ __launch_bounds__(512, 4) void gemm_kernel(
    const float* __restrict__ x, const _Float16* __restrict__ whF,
    const _Float16* __restrict__ wlF, float* __restrict__ partial,
    int K_slice)
{
    __shared__ _Float16 XhL[2][TM * XP];
    __shared__ _Float16 XlL[2][TM * XP];

    const int tid  = threadIdx.x;
    const int lane = tid & 63;
    const int wid  = tid >> 6;            // wave id 0..7 -> 32-expert tile
    const int t0   = blockIdx.x * TM;
    const int ks   = blockIdx.y;
    const int kbeg = ks * K_slice;
    const int nchunks = K_slice >> 5;     // even for kslices in {1,2,4,8}

    const int m32 = lane & 31;            // token row within 32-tile
    const int kh  = lane >> 5;            // k-half -> k offset kh*8

    float16_ acc[2];
    acc[0] = (float16_)0.0f;
    acc[1] = (float16_)0.0f;

    // Coalesced staging: thread -> one float4; row = tid>>3, c4 = tid&7
    const int srow = tid >> 3;
    const int sc4  = tid & 7;
    const float* xl = x + (size_t)(t0 + srow) * ND + kbeg + sc4 * 4;

    // B fragment base for this wave's n-tile; chunk c adds c*1024 (+512 for kstep 1)
    const size_t bbase = ((size_t)(wid * NKT16 + (kbeg >> 4)) * 64 + lane) * 8;
    const _Float16* bhp = whF + bbase;
    const _Float16* blp = wlF + bbase;

    float4 xv[2];          // [slot] raw fp32 x staging regs
    half8_ Bf[2][4];       // [slot][kstep*2 + (0=hi,1=lo)]

    // Prologue: x(0)->slot0, x(1)->slot1, B(0)->slot0; stage x(0) -> LDS buf0.
    xv[0] = *reinterpret_cast<const float4*>(xl);
    xv[1] = *reinterpret_cast<const float4*>(xl + 32);
    #pragma unroll
    for (int kk = 0; kk < 2; ++kk) {
        Bf[0][kk * 2 + 0] = *reinterpret_cast<const half8_*>(bhp + kk * 512);
        Bf[0][kk * 2 + 1] = *reinterpret_cast<const half8_*>(blp + kk * 512);
    }
    {
        const float vs[4] = {xv[0].x, xv[0].y, xv[0].z, xv[0].w};
        half4_ h, l;
        #pragma unroll
        for (int j = 0; j < 4; ++j) {
            const _Float16 hi = (_Float16)vs[j];
            h[j] = hi; l[j] = (_Float16)(vs[j] - (float)hi);
        }
        *reinterpret_cast<half4_*>(&XhL[0][srow * XP + sc4 * 4]) = h;
        *reinterpret_cast<half4_*>(&XlL[0][srow * XP + sc4 * 4]) = l;
    }
    __syncthreads();

#define STEP(P, C)                                                             \
    {                                                                          \
        /* A-frags for chunk C from LDS buf P (after barrier) */               \
        half8_ ah[2][2], al[2][2]; /* [mt][kstep] */                           \
        _Pragma("unroll")                                                      \
        for (int mt = 0; mt < 2; ++mt)                                         \
            _Pragma("unroll")                                                  \
            for (int kk = 0; kk < 2; ++kk) {                                   \
                const int ao = (mt * 32 + m32) * XP + kh * 8 + kk * 16;        \
                ah[mt][kk] = *reinterpret_cast<const half8_*>(&XhL[P][ao]);    \
                al[mt][kk] = *reinterpret_cast<const half8_*>(&XlL[P][ao]);    \
            }                                                                  \
        /* issue x(C+2) -> slot P */                                           \
        if ((C) + 2 < nchunks)                                                 \
            xv[P] = *reinterpret_cast<const float4*>(xl + ((C) + 2) * 32);     \
        /* issue B(C+1) -> slot P^1 */                                         \
        if ((C) + 1 < nchunks) {                                               \
            _Pragma("unroll")                                                  \
            for (int kk = 0; kk < 2; ++kk) {                                   \
                Bf[(P) ^ 1][kk * 2 + 0] = *reinterpret_cast<const half8_*>(    \
                    bhp + ((C) + 1) * 1024 + kk * 512);                        \
                Bf[(P) ^ 1][kk * 2 + 1] = *reinterpret_cast<const half8_*>(    \
                    blp + ((C) + 1) * 1024 + kk * 512);                        \
            }                                                                  \
        }                                                                      \
        /* MFMA: product-major, 4 independent between dependent accumulates */ \
        _Pragma("unroll")                                                      \
        for (int kk = 0; kk < 2; ++kk)                                         \
            _Pragma("unroll")                                                  \
            for (int mt = 0; mt < 2; ++mt)                                     \
                acc[mt] = __builtin_amdgcn_mfma_f32_32x32x16_f16(              \
                    ah[mt][kk], Bf[P][kk * 2 + 0], acc[mt], 0, 0, 0);          \
        _Pragma("unroll")                                                      \
        for (int kk = 0; kk < 2; ++kk)                                         \
            _Pragma("unroll")                                                  \
            for (int mt = 0; mt < 2; ++mt)                                     \
                acc[mt] = __builtin_amdgcn_mfma_f32_32x32x16_f16(              \
                    al[mt][kk], Bf[P][kk * 2 + 0], acc[mt], 0, 0, 0);          \
        _Pragma("unroll")                                                      \
        for (int kk = 0; kk < 2; ++kk)                                         \
            _Pragma("unroll")                                                  \
            for (int mt = 0; mt < 2; ++mt)                                     \
                acc[mt] = __builtin_amdgcn_mfma_f32_32x32x16_f16(              \
                    ah[mt][kk], Bf[P][kk * 2 + 1], acc[mt], 0, 0, 0);          \
        /* stage x(C+1) from slot P^1 -> LDS buf P^1 */                        \
        if ((C) + 1 < nchunks) {                                               \
            const float vs[4] = {xv[(P) ^ 1].x, xv[(P) ^ 1].y,                 \
                                 xv[(P) ^ 1].z, xv[(P) ^ 1].w};                \
            half4_ h, l;                                                       \
            _Pragma("unroll")                                                  \
            for (int j = 0; j < 4; ++j) {                                      \
                const _Float16 hi = (_Float16)vs[j];                           \
                h[j] = hi; l[j] = (_Float16)(vs[j] - (float)hi);               \
            }                                                                  \
            *reinterpret_cast<half4_*>(&XhL[(P) ^ 1][srow * XP + sc4 * 4]) = h;\
            *reinterpret_cast<half4_*>(&XlL[(P) ^ 1][srow * XP + sc4 * 4]) = l;\
        }                                                                      \
        __syncthreads();                                                       \
    }

    for (int c = 0; c < nchunks; c += 2) {
        STEP(0, c)
        STEP(1, c + 1)
    }
#undef STEP

    // Epilogue: 32x32 C/D layout: col = lane&31, row = (reg&3)+8*(reg>>2)+4*(lane>>5)
    const int e = wid * 32 + m32;
    #pragma unroll
    for (int mt = 0; mt < 2; ++mt) {
        #pragma unroll
        for (int r = 0; r < 16; ++r) {
            const int row = (r & 3) + 8 * (r >> 2) + 4 * kh;
            const int t = t0 + mt * 32 + row;
            partial[((size_t)ks * TT + t) * NE + e] = acc[mt][r];
        }
    }
}

// ---------------------------------------------------------------------------
// Routing: one 64-lane wave per token; lane handles 4 experts.
__global__ __launch_bounds__(256) void routing_kernel(
    const float* __restrict__ partial, const float* __restrict__ bias,
    float* __restrict__ out_w, float* __restrict__ out_i, int kslices)
{
    const int lane = threadIdx.x & 63;
    const int t = blockIdx.x * 4 + (threadIdx.x >> 6);

    float4 a = make_float4(0.f, 0.f, 0.f, 0.f);
    for (int s = 0; s < kslices; ++s) {
        const float4 p = *reinterpret_cast<const float4*>(
            partial + ((size_t)s * TT + t) * NE + lane * 4);
        a.x += p.x; a.y += p.y; a.z += p.z; a.w += p.w;
    }
    const float4 b4 = *reinterpret_cast<const float4*>(bias + lane * 4);
    const float lg[4] = {a.x, a.y, a.z, a.w};
    const float bs[4] = {b4.x, b4.y, b4.z, b4.w};
    float sg[4], sv[4];
    #pragma unroll
    for (int j = 0; j < 4; ++j) {
        sg[j] = 1.0f / (1.0f + expf(-lg[j]));   // original sigmoid score
        sv[j] = sg[j] + bs[j];                  // biased score
    }

    // Per-group (8 lanes = 32 experts) top-2 sum
    float m1 = -1e30f, m2 = -1e30f;
    #pragma unroll
    for (int j = 0; j < 4; ++j) {
        if (sv[j] > m1)      { m2 = m1; m1 = sv[j]; }
        else if (sv[j] > m2) { m2 = sv[j]; }
    }
    #pragma unroll
    for (int off = 1; off <= 4; off <<= 1) {
        const float o1 = __shfl_xor(m1, off, 64);
        const float o2 = __shfl_xor(m2, off, 64);
        if (o1 > m1) { m2 = fmaxf(m1, o2); m1 = o1; }
        else         { m2 = fmaxf(m2, o1); }
    }
    const float gs = m1 + m2;

    // All 8 group scores on every lane; serial top-4 (lowest index on ties)
    float gv[NGRP];
    #pragma unroll
    for (int g = 0; g < NGRP; ++g) gv[g] = __shfl(gs, g * 8, 64);
    unsigned keep = 0;
    #pragma unroll
    for (int r = 0; r < TOPKG; ++r) {
        int best = 0; float bvv = -1e30f;
        #pragma unroll
        for (int g = 0; g < NGRP; ++g) {
            const bool taken = (keep >> g) & 1u;
            if (!taken && gv[g] > bvv) { bvv = gv[g]; best = g; }
        }
        keep |= 1u << best;
    }

    // Masked scores (exact 0.0f for dropped groups, matching sg*mask)
    const bool kept = (keep >> (lane >> 3)) & 1u;
    float rv[4];
    #pragma unroll
    for (int j = 0; j < 4; ++j) rv[j] = kept ? sv[j] : 0.0f;

    // 8x wave argmax extraction carrying (biased val, idx, orig sigmoid)
    float wsum = 0.f, myw = 0.f;
    int myi = 0;
    #pragma unroll
    for (int r = 0; r < TOPK; ++r) {
        float bv = -1e30f, bo = 0.f; int bi = 0x7fffffff;
        #pragma unroll
        for (int j = 0; j < 4; ++j)
            if (rv[j] > bv) { bv = rv[j]; bi = lane * 4 + j; bo = sg[j]; }
        #pragma unroll
        for (int off = 1; off < 64; off <<= 1) {
            const float ov = __shfl_xor(bv, off, 64);
            const int   oi = __shfl_xor(bi, off, 64);
            const float oo = __shfl_xor(bo, off, 64);
            if (ov > bv || (ov == bv && oi < bi)) { bv = ov; bi = oi; bo = oo; }
        }
        if ((bi >> 2) == lane) rv[bi & 3] = -1e30f;   // remove winner
        wsum += bo;
        if (lane == r) { myw = bo; myi = bi; }
    }
    const float scale = ROUTE_SCALE / wsum;
    if (lane < TOPK) {
        out_w[(size_t)t * TOPK + lane] = myw * scale;
        out_i[(size_t)t * TOPK + lane] = (float)myi;  // fp32-encoded indices
    }
}

// ---------------------------------------------------------------------------
extern "C" void kernel_launch(void* const* d_in, const int* in_sizes, int n_in,
                              void* d_out, int out_size, void* d_ws, size_t ws_size,
                              hipStream_t stream) {
    const float* x    = (const float*)d_in[0];
    const float* w    = (const float*)d_in[1];
    const float* bias = (const float*)d_in[2];

    float* out_w = (float*)d_out;
    float* out_i = (float*)d_out + (size_t)TT * TOPK;

    // ws layout: whF | wlF | partial[kslices][TT][NE]
    const size_t wfrag_bytes = (size_t)NE * ND * sizeof(_Float16);  // 3.67 MB
    _Float16* whF = (_Float16*)d_ws;
    _Float16* wlF = (_Float16*)((char*)d_ws + wfrag_bytes);
    float* partial = (float*)((char*)d_ws + 2 * wfrag_bytes);

    const size_t part1 = (size_t)TT * NE * sizeof(float);           // 8 MB
    int kslices = 1;
    if      (ws_size >= 2 * wfrag_bytes + 8 * part1) kslices = 8;
    else if (ws_size >= 2 * wfrag_bytes + 4 * part1) kslices = 4;
    else if (ws_size >= 2 * wfrag_bytes + 2 * part1) kslices = 2;
    const int K_slice = ND / kslices;

    conv_w_kernel<<<(NNT32 * NKT16 * 64) / 256, 256, 0, stream>>>(w, whF, wlF);

    dim3 ggrid(TT / TM, kslices);   // (128, kslices)
    gemm_kernel<<<ggrid, 512, 0, stream>>>(x, whF, wlF, partial, K_slice);

    routing_kernel<<<TT / 4, 256, 0, stream>>>(partial, bias, out_w, out_i, kslices);
}